// Round 16
// baseline (64.282 us; speedup 1.0000x reference)
//
#include <hip/hip_runtime.h>

// DecisionTreePolicy — complete binary tree, depth 15 (32767 nodes).
// Internal 0..16382 (children 2i+1/2i+2), leaves 16383..32766 -> exactly 14
// decisions from root; out[b] = leaf_logits[leaf(b)].
//
// History: R1/R2 gathers 84us. R4 LDS-stream 68.5. R7 counted-vmcnt 67.2.
// R11 2 waves/SIMD partitioned rows 64.5. R13 barrier-free per-wave DMA 62.4.
// R15 store-after-traverse + 1040B row pad 60.8 (best; effective BW 5.6 TB/s
// = 89% of copy ceiling). R16 = R15 + (1) NT cache policy (aux=2) on the obs
// DMA: the 256MB zero-reuse stream no longer evicts the 4.2MB leaf_logits
// working set from L2/L3 -> gathers stay cache-hot, no HBM re-fetch;
// (2) gather + dma(h+1) issued BEFORE the dma(h) wait (both independent of
// it) -> their latency overlaps the wait; counted vmcnt(6) never drains.

#define N_INTERN  16383
#define N_FEAT    256
#define N_ACT     64
#define BATCH     262144
#define BLOCK     512
#define GRID      256
#define ROWS_PB   (BATCH / GRID)      // 1024 rows per block
#define HROWS     32                  // rows per half-tile
#define HALVES    (ROWS_PB / HROWS)   // 32
#define DEPTH     14
#define RPAD      260                 // padded row stride in floats (1040 B)

typedef float f32x4 __attribute__((ext_vector_type(4)));
typedef __attribute__((address_space(3))) void        lds_void_t;
typedef const __attribute__((address_space(1))) void  glob_cvoid_t;

__device__ __forceinline__ void gload16_nt(const void* g, void* l) {
    // async global->LDS DMA, NT cache policy (gfx950 CPol bit1 = NT):
    // streams past L2/L3 without evicting the leaf_logits working set.
    __builtin_amdgcn_global_load_lds((glob_cvoid_t*)g, (lds_void_t*)l, 16, 0, 2);
}

__global__ __launch_bounds__(BLOCK, 1) void tree_policy_kernel(
    const float* __restrict__ obs,          // [BATCH][N_FEAT]
    const int*   __restrict__ features,     // [N_NODES]
    const float* __restrict__ thresholds,   // [N_NODES]
    const float* __restrict__ leaf_logits,  // [N_NODES][N_ACT]
    float*       __restrict__ out)          // [BATCH][N_ACT]
{
    __shared__ float         sthr [N_INTERN];        // 64 KB
    __shared__ unsigned char sfeat[N_INTERN];        // 16 KB
    __shared__ __align__(16) float buf[2][HROWS * RPAD];  // 2 x 33.3 KB -> 146.6 KB

    const int tid  = threadIdx.x;
    const int lane = tid & 63;
    const int wave = tid >> 6;                // 0..7; 2 waves/SIMD
    const long rowBase = (long)blockIdx.x * ROWS_PB;

    // ---- tree -> LDS (cooperative, one-time) ----
    for (int i = tid; i < N_INTERN; i += BLOCK) {
        sthr[i]  = thresholds[i];
        sfeat[i] = (unsigned char)features[i];
    }
    const float thr_root  = thresholds[0];
    const int   feat_root = features[0];

    // Row ownership: wave w stages AND traverses rows [4w, 4w+4) of each half.
    const int myrow_id = (wave << 2) | (lane >> 4);   // 0..31
    const int chunk    = lane & 15;                   // this lane's f32x4 chunk

    // Per-wave DMA of its own 4 rows of half h (4 x 1KB; padded LDS stride).
    auto dma = [&](int h) {
        const float* g = obs + (rowBase + (long)h * HROWS + (wave << 2)) * N_FEAT + lane * 4;
        char* l = (char*)&buf[h & 1][(wave << 2) * RPAD];
#pragma unroll
        for (int k = 0; k < 4; ++k)
            gload16_nt(g + k * N_FEAT, l + k * (RPAD * 4));
    };

    // Child-prefetch traversal: obs lookup (fcur in register) runs parallel
    // to children's thr/feat reads -> one dependent LDS round-trip per level.
    auto traverse = [&](int h) -> int {
        const float* myrow = &buf[h & 1][myrow_id * RPAD];
        int node = 0; float tcur = thr_root; int fcur = feat_root;
#pragma unroll
        for (int d = 0; d < DEPTH - 1; ++d) {
            const float x   = myrow[fcur];
            const int   c   = 2 * node + 1;
            const float tl  = sthr[c];
            const float trr = sthr[c + 1];
            const int   fl  = sfeat[c];
            const int   fr  = sfeat[c + 1];
            const bool  L   = (x <= tcur);          // reference NaN semantics
            node = L ? c : c + 1;
            tcur = L ? tl : trr;
            fcur = L ? fl : fr;
        }
        const float x = myrow[fcur];                 // last level: children = leaves
        return 2 * node + ((x <= tcur) ? 1 : 2);
    };

    // ---- prologue ----
    dma(0);
    asm volatile("s_waitcnt vmcnt(0) lgkmcnt(0)" ::: "memory");
    __builtin_amdgcn_s_barrier();        // the ONLY barrier: tree visible to all
    dma(1);
    __builtin_amdgcn_sched_barrier(0);
    int node_prev = traverse(0);

    for (int h = 1; h < HALVES; ++h) {
        // G(h-1): issue the leaf gather BEFORE the dma-wait (depends only on
        // node_prev); its L2 latency overlaps the wait + traversal.
        const f32x4 v = *(const f32x4*)(leaf_logits + (size_t)node_prev * N_ACT + chunk * 4);
        __builtin_amdgcn_sched_barrier(0);
        // DMA(h+1): also issued pre-wait (writes the buffer this wave finished
        // reading at h-1; wave-private rows -> no cross-wave hazard).
        if (h + 1 < HALVES) dma(h + 1);
        __builtin_amdgcn_sched_barrier(0);
        // Counted wait: dma(h) retired. Younger suffix stays in flight:
        // store(h-2) + gather(h-1) + dma(h+1) = 6 (5 at h=1; 2 at h=31).
        if (h == 1)               asm volatile("s_waitcnt vmcnt(5)" ::: "memory");
        else if (h == HALVES - 1) asm volatile("s_waitcnt vmcnt(2)" ::: "memory");
        else                      asm volatile("s_waitcnt vmcnt(6)" ::: "memory");
        __builtin_amdgcn_sched_barrier(0);
        const int node_cur = traverse(h);            // LDS-only
        __builtin_amdgcn_sched_barrier(0);
        // S(h-1): store after traverse; its wait-for-gather is vmcnt(4)
        // (dma(h+1) is younger than the gather) -> pipeline never drains.
        const long orow = rowBase + (long)(h - 1) * HROWS + myrow_id;
        __builtin_nontemporal_store(v, (f32x4*)(out + orow * N_ACT + chunk * 4));
        __builtin_amdgcn_sched_barrier(0);
        node_prev = node_cur;
    }

    // final epilogue (half HALVES-1)
    const f32x4 v = *(const f32x4*)(leaf_logits + (size_t)node_prev * N_ACT + chunk * 4);
    const long orow = rowBase + (long)(HALVES - 1) * HROWS + myrow_id;
    __builtin_nontemporal_store(v, (f32x4*)(out + orow * N_ACT + chunk * 4));
}

extern "C" void kernel_launch(void* const* d_in, const int* in_sizes, int n_in,
                              void* d_out, int out_size, void* d_ws, size_t ws_size,
                              hipStream_t stream) {
    const float* obs         = (const float*)d_in[0];
    const int*   features    = (const int*)  d_in[1];
    const float* thresholds  = (const float*)d_in[2];
    // d_in[3]/d_in[4] (children) unused: tree is complete by construction.
    const float* leaf_logits = (const float*)d_in[5];
    float*       out         = (float*)d_out;

    tree_policy_kernel<<<dim3(GRID), dim3(BLOCK), 0, stream>>>(
        obs, features, thresholds, leaf_logits, out);
}

// Round 17
// 60.660 us; speedup vs baseline: 1.0597x; 1.0597x over previous
//
#include <hip/hip_runtime.h>

// DecisionTreePolicy — complete binary tree, depth 15 (32767 nodes).
// Internal 0..16382 (children 2i+1/2i+2), leaves 16383..32766 -> exactly 14
// decisions from root; out[b] = leaf_logits[leaf(b)].
//
// FINAL (R15 structure, reverted after R16's NT-policy regression):
//  - obs streamed through LDS once, coalesced (256 MB compulsory), via
//    per-wave global_load_lds DMA: wave w stages AND traverses only rows
//    [4w,4w+4) of each 32-row half-tile -> no cross-wave deps, ONE barrier
//    in the whole kernel (tree visibility).
//  - whole tree in LDS (thr f32 64KB + feat u8 16KB); traversal =
//    child-prefetch form, one dependent LDS round-trip per level.
//  - 2 waves/SIMD hide each other's dependent chains (R11 win).
//  - LDS rows padded to 1040B: converged-level reads conflict-free (R15 win).
//  - leaf gather issued after the counted dma-wait, consumed after traverse
//    -> its latency hides under the traversal (R15 win); counted vmcnt(1)
//    never drains the pipeline (R7/T4 lesson).
// 60.8us = 340 MB @ 5.6 TB/s effective = 89% of the 6.3 TB/s copy ceiling.

#define N_INTERN  16383
#define N_FEAT    256
#define N_ACT     64
#define BATCH     262144
#define BLOCK     512
#define GRID      256
#define ROWS_PB   (BATCH / GRID)      // 1024 rows per block
#define HROWS     32                  // rows per half-tile
#define HALVES    (ROWS_PB / HROWS)   // 32
#define DEPTH     14
#define RPAD      260                 // padded row stride in floats (1040 B)

typedef float f32x4 __attribute__((ext_vector_type(4)));
typedef __attribute__((address_space(3))) void        lds_void_t;
typedef const __attribute__((address_space(1))) void  glob_cvoid_t;

__device__ __forceinline__ void gload16(const void* g, void* l) {
    // async global->LDS DMA: per-lane global addr, wave-uniform LDS base,
    // HW writes lds_base + lane*16 (1 KB per instruction per wave).
    __builtin_amdgcn_global_load_lds((glob_cvoid_t*)g, (lds_void_t*)l, 16, 0, 0);
}

__global__ __launch_bounds__(BLOCK, 1) void tree_policy_kernel(
    const float* __restrict__ obs,          // [BATCH][N_FEAT]
    const int*   __restrict__ features,     // [N_NODES]
    const float* __restrict__ thresholds,   // [N_NODES]
    const float* __restrict__ leaf_logits,  // [N_NODES][N_ACT]
    float*       __restrict__ out)          // [BATCH][N_ACT]
{
    __shared__ float         sthr [N_INTERN];        // 64 KB
    __shared__ unsigned char sfeat[N_INTERN];        // 16 KB
    __shared__ __align__(16) float buf[2][HROWS * RPAD];  // 2 x 33.3 KB -> 146.6 KB

    const int tid  = threadIdx.x;
    const int lane = tid & 63;
    const int wave = tid >> 6;                // 0..7; 2 waves/SIMD
    const long rowBase = (long)blockIdx.x * ROWS_PB;

    // ---- tree -> LDS (cooperative, one-time) ----
    for (int i = tid; i < N_INTERN; i += BLOCK) {
        sthr[i]  = thresholds[i];
        sfeat[i] = (unsigned char)features[i];
    }
    const float thr_root  = thresholds[0];
    const int   feat_root = features[0];

    // Row ownership: wave w stages AND traverses rows [4w, 4w+4) of each half.
    const int myrow_id = (wave << 2) | (lane >> 4);   // 0..31
    const int chunk    = lane & 15;                   // this lane's f32x4 chunk

    // Per-wave DMA of its own 4 rows of half h (4 x 1KB; padded LDS stride).
    auto dma = [&](int h) {
        const float* g = obs + (rowBase + (long)h * HROWS + (wave << 2)) * N_FEAT + lane * 4;
        char* l = (char*)&buf[h & 1][(wave << 2) * RPAD];
#pragma unroll
        for (int k = 0; k < 4; ++k)
            gload16(g + k * N_FEAT, l + k * (RPAD * 4));
    };

    // Child-prefetch traversal: obs lookup (fcur in register) runs parallel
    // to children's thr/feat reads -> one dependent LDS round-trip per level.
    auto traverse = [&](int h) -> int {
        const float* myrow = &buf[h & 1][myrow_id * RPAD];
        int node = 0; float tcur = thr_root; int fcur = feat_root;
#pragma unroll
        for (int d = 0; d < DEPTH - 1; ++d) {
            const float x   = myrow[fcur];
            const int   c   = 2 * node + 1;
            const float tl  = sthr[c];
            const float trr = sthr[c + 1];
            const int   fl  = sfeat[c];
            const int   fr  = sfeat[c + 1];
            const bool  L   = (x <= tcur);          // reference NaN semantics
            node = L ? c : c + 1;
            tcur = L ? tl : trr;
            fcur = L ? fl : fr;
        }
        const float x = myrow[fcur];                 // last level: children = leaves
        return 2 * node + ((x <= tcur) ? 1 : 2);
    };

    // ---- prologue ----
    dma(0);
    asm volatile("s_waitcnt vmcnt(0) lgkmcnt(0)" ::: "memory");
    __builtin_amdgcn_s_barrier();        // the ONLY barrier: tree visible to all
    dma(1);
    __builtin_amdgcn_sched_barrier(0);
    int node_prev = traverse(0);

    for (int h = 1; h < HALVES; ++h) {
        // Own-wave wait: DMA(h) landed (issued a full period ago). h>=2: allow
        // 1 outstanding = previous output store (never drained in-loop).
        if (h == 1) asm volatile("s_waitcnt vmcnt(0)" ::: "memory");
        else        asm volatile("s_waitcnt vmcnt(1)" ::: "memory");
        __builtin_amdgcn_sched_barrier(0);
        // G(h-1): leaf gather issued now, consumed after traverse — its
        // latency hides under the traversal; wait leaves DMA(h+1) flying.
        const f32x4 v = *(const f32x4*)(leaf_logits + (size_t)node_prev * N_ACT + chunk * 4);
        __builtin_amdgcn_sched_barrier(0);
        if (h + 1 < HALVES) {
            dma(h + 1);
            __builtin_amdgcn_sched_barrier(0);
        }
        const int node_cur = traverse(h);            // LDS-only, ~0.8us
        __builtin_amdgcn_sched_barrier(0);
        // S(h-1): store after traverse; compiler's wait-for-gather is free now.
        const long orow = rowBase + (long)(h - 1) * HROWS + myrow_id;
        __builtin_nontemporal_store(v, (f32x4*)(out + orow * N_ACT + chunk * 4));
        __builtin_amdgcn_sched_barrier(0);
        node_prev = node_cur;
    }

    // final epilogue (half HALVES-1)
    const f32x4 v = *(const f32x4*)(leaf_logits + (size_t)node_prev * N_ACT + chunk * 4);
    const long orow = rowBase + (long)(HALVES - 1) * HROWS + myrow_id;
    __builtin_nontemporal_store(v, (f32x4*)(out + orow * N_ACT + chunk * 4));
}

extern "C" void kernel_launch(void* const* d_in, const int* in_sizes, int n_in,
                              void* d_out, int out_size, void* d_ws, size_t ws_size,
                              hipStream_t stream) {
    const float* obs         = (const float*)d_in[0];
    const int*   features    = (const int*)  d_in[1];
    const float* thresholds  = (const float*)d_in[2];
    // d_in[3]/d_in[4] (children) unused: tree is complete by construction.
    const float* leaf_logits = (const float*)d_in[5];
    float*       out         = (float*)d_out;

    tree_policy_kernel<<<dim3(GRID), dim3(BLOCK), 0, stream>>>(
        obs, features, thresholds, leaf_logits, out);
}